// Round 14
// baseline (211.482 us; speedup 1.0000x reference)
//
#include <hip/hip_runtime.h>

// Wavelet_Convolution: out = relu(phi1 @ (kernel * (phi0 @ (x @ W))))
// N=100000, F=128, NNZ=1.6M per sparse matrix (COO, int32 idx, f32 vals).
//
// Pipeline (4 dispatches):
//   1) scatter_transpose: [blocks 0..63] Wt = bf16(W^T);
//      [rest] per 7168-edge chunk: group records by 256-row bucket in LDS,
//      flush block-contiguous into d_out-as-scratch (fully coalesced).
//   2) sort_gemm (fused): bucket_sort both matrices || X'(bf16) = x@W (MFMA)
//   3) spmm_csr: Xt(bf16) = kernel * (phi0 @ X')  — 16 lanes/row, 8-wide MLP
//   4) spmm_csr: out(f32) = relu(phi1 @ Xt) — overwrites dead scratch.

constexpr int kN = 100000;
constexpr int kF = 128;
constexpr int kNNZ = 1600000;

constexpr int kBuckets = (kN + 255) / 256;                  // 391 (256-row buckets)
constexpr int kBucketCap = 4608;                            // mean 4096 + 8 sigma
constexpr int kChunk = 7168;                                // edges per scatter block
constexpr int kChunkBlocks = (kNNZ + kChunk - 1) / kChunk;  // 224 per matrix
constexpr int kSlotsPerMat = kChunkBlocks * kChunk;         // 1,605,632
constexpr int kDirStride = kBuckets + 1;                    // 392 entries per chunk
constexpr int kTransBlocks = 64;
constexpr int kSortBlocks = 2 * kBuckets;                   // 782
constexpr int kGemmBlocks = (kN + 127) / 128;               // 782 (128 rows, 512 thr)
constexpr int kRowBlocks16 = kN * 16 / 256;                 // 6250 (16 lanes/row)

typedef short bf16x8 __attribute__((ext_vector_type(8)));
typedef float f32x4 __attribute__((ext_vector_type(4)));
typedef unsigned short ushort4v __attribute__((ext_vector_type(4)));
typedef unsigned short ushort8v __attribute__((ext_vector_type(8)));

__device__ __forceinline__ unsigned short f32_to_bf16(float f) {
    unsigned int u = __float_as_uint(f);
    u += 0x7fffu + ((u >> 16) & 1u);   // round-to-nearest-even
    return (unsigned short)(u >> 16);
}
__device__ __forceinline__ float bf16_to_f32(unsigned short h) {
    return __uint_as_float((unsigned int)h << 16);
}

// ---------------------------------------------------------------------------
// Dispatch 1: W transpose (blocks 0..63) + coalesced bucket scatter (rest).
// Record: hi32 = f32 val, lo32 = (localrow&255)<<17 | col (col < 2^17).
// ---------------------------------------------------------------------------
__global__ __launch_bounds__(256) void scatter_transpose(
    const float* __restrict__ W, unsigned short* __restrict__ Wt,
    const int* __restrict__ r0, const int* __restrict__ c0, const float* __restrict__ v0,
    const int* __restrict__ r1, const int* __restrict__ c1, const float* __restrict__ v1,
    unsigned long long* __restrict__ stg, unsigned short* __restrict__ dir) {
    const int t = threadIdx.x;
    if (blockIdx.x < kTransBlocks) {
        const int e = blockIdx.x * 256 + t;
        const int n = e & 127, k = e >> 7;
        Wt[n * 128 + k] = f32_to_bf16(W[e]);
        return;
    }

    __shared__ unsigned long long recs[kChunk];   // 56 KB
    __shared__ int hist[kDirStride];
    __shared__ int cur[kDirStride];
    __shared__ int sc2[256];

    const int b = blockIdx.x - kTransBlocks;      // 0..447
    const bool m1 = b >= kChunkBlocks;
    const int cb = m1 ? b - kChunkBlocks : b;
    const int* rows = m1 ? r1 : r0;
    const int* cols = m1 ? c1 : c0;
    const float* vals = m1 ? v1 : v0;
    unsigned long long* dst = stg + (size_t)b * kChunk;      // block-contiguous
    unsigned short* dirm = dir + (size_t)b * kDirStride;

    for (int i = t; i < kDirStride; i += 256) hist[i] = 0;
    __syncthreads();

    const int base0 = cb * kChunk;
    const int cnt = min(kNNZ - base0, kChunk);

    for (int j = t; j < cnt; j += 256) atomicAdd(&hist[rows[base0 + j] >> 8], 1);
    __syncthreads();

    // scan 392 bins (threads 0..195 own bins 2t, 2t+1)
    int s = 0;
    if (t < 196) s = hist[2 * t] + hist[2 * t + 1];
    sc2[t] = (t < 196) ? s : 0;
    __syncthreads();
    #pragma unroll
    for (int off = 1; off < 256; off <<= 1) {
        const int add = (t >= off) ? sc2[t - off] : 0;
        __syncthreads();
        sc2[t] += add;
        __syncthreads();
    }
    if (t < 196) {
        const int ex = sc2[t] - s;
        cur[2 * t] = ex;
        cur[2 * t + 1] = ex + hist[2 * t];
        dirm[2 * t] = (unsigned short)ex;
        dirm[2 * t + 1] = (unsigned short)(ex + hist[2 * t]);
    }
    __syncthreads();

    for (int j = t; j < cnt; j += 256) {
        const int idx = base0 + j;
        const int r = rows[idx];
        const int bk = r >> 8;
        const int pos = atomicAdd(&cur[bk], 1);
        const unsigned int key = ((unsigned int)(r & 255) << 17) | (unsigned int)cols[idx];
        recs[pos] = ((unsigned long long)__float_as_uint(vals[idx]) << 32) | key;
    }
    __syncthreads();

    for (int j = t; j < cnt; j += 256) dst[j] = recs[j];
}

// ---------------------------------------------------------------------------
// Dispatch 2 (fused): bucket_sort (blocks 0..781) || gemm (blocks 782..1563).
// ---------------------------------------------------------------------------
__global__ __launch_bounds__(512) void sort_gemm(
    const unsigned long long* __restrict__ stg,
    const unsigned short* __restrict__ dir,
    unsigned long long* __restrict__ sortedG,
    int* __restrict__ rs, int* __restrict__ re,
    const float* __restrict__ x, const unsigned short* __restrict__ Wt,
    unsigned short* __restrict__ Xpb) {
    __shared__ __align__(16) char smem[41728];
    const int t = threadIdx.x;

    if (blockIdx.x < kSortBlocks) {
        // ================= sort branch =================
        unsigned long long* sorted = (unsigned long long*)smem;       // 36864 B
        int* rlen = (int*)(smem + 36864);                             // 896 B
        int* gst  = (int*)(smem + 36864 + 896);                       // 896 B
        int* hist = (int*)(smem + 36864 + 1792);                      // 1024 B
        int* sc   = (int*)(smem + 36864 + 2816);                      // 1024 B
        int* cur  = (int*)(smem + 36864 + 3840);                      // 1024 B

        const int bidx = blockIdx.x;
        const bool m1 = bidx >= kBuckets;
        const int bk = m1 ? bidx - kBuckets : bidx;
        const unsigned long long* stgm = stg + (m1 ? (size_t)kSlotsPerMat : 0);

        if (t < kChunkBlocks) {
            const unsigned short* dd =
                dir + (size_t)((m1 ? kChunkBlocks : 0) + t) * kDirStride;
            const int s = dd[bk];
            rlen[t] = dd[bk + 1] - s;
            gst[t] = t * kChunk + s;
        }
        if (t < 256) hist[t] = 0;
        __syncthreads();

        const int g = t >> 5;        // 16 groups of 32 lanes
        const int lane = t & 31;

        for (int blk = g; blk < kChunkBlocks; blk += 16) {
            const int len = rlen[blk];
            const int gs = gst[blk];
            for (int i = lane; i < len; i += 32) {
                const unsigned int lo = (unsigned int)stgm[gs + i];
                atomicAdd(&hist[(lo >> 17) & 255], 1);
            }
        }
        __syncthreads();

        const int v = (t < 256) ? hist[t] : 0;
        if (t < 256) sc[t] = v;
        __syncthreads();
        #pragma unroll
        for (int off = 1; off < 256; off <<= 1) {
            const int add = (t < 256 && t >= off) ? sc[t - off] : 0;
            __syncthreads();
            if (t < 256) sc[t] += add;
            __syncthreads();
        }
        if (t < 256) cur[t] = sc[t] - v;   // exclusive
        __syncthreads();

        for (int blk = g; blk < kChunkBlocks; blk += 16) {
            const int len = rlen[blk];
            const int gs = gst[blk];
            for (int i = lane; i < len; i += 32) {
                const unsigned long long p = stgm[gs + i];
                const int lrow = (int)(((unsigned int)p >> 17) & 255);
                sorted[atomicAdd(&cur[lrow], 1)] = p;
            }
        }
        __syncthreads();

        const int nrec = sc[255];
        const size_t outBase = (size_t)bidx * kBucketCap;
        for (int j = t; j < nrec; j += 512) sortedG[outBase + j] = sorted[j];
        if (t < 256) {
            const int row = bk * 256 + t;
            if (row < kN) {
                const int rg = (m1 ? kN : 0) + row;
                rs[rg] = (int)outBase + sc[t] - hist[t];
                re[rg] = (int)outBase + sc[t];
            }
        }
    } else {
        // ================= gemm branch (128 rows, 8 waves) =================
        unsigned short* xs = (unsigned short*)smem;     // 128x128 bf16 = 32 KB
        const int rowBase = (blockIdx.x - kSortBlocks) * 128;

        {
            const int lrow = t >> 2;                    // 0..127
            const int q = t & 3;
            int srow = rowBase + lrow;
            if (srow >= kN) srow = kN - 1;
            const float4* xr = (const float4*)(x + (size_t)srow * kF) + q * 8;
            #pragma unroll
            for (int i = 0; i < 8; ++i) {
                const float4 f = xr[i];
                ushort4v h;
                h.x = f32_to_bf16(f.x); h.y = f32_to_bf16(f.y);
                h.z = f32_to_bf16(f.z); h.w = f32_to_bf16(f.w);
                const int kidx = q * 32 + i * 4;
                *(ushort4v*)&xs[lrow * 128 + (kidx ^ ((lrow & 7) << 3))] = h;
            }
        }
        __syncthreads();

        const int w = t >> 6;        // wave 0..7 -> rows w*16..w*16+15
        const int l = t & 63;
        const int lr = l & 15;
        const int lq = l >> 4;

        f32x4 acc[8];
        #pragma unroll
        for (int n = 0; n < 8; ++n) acc[n] = (f32x4){0.f, 0.f, 0.f, 0.f};

        const int arow = w * 16 + lr;
        #pragma unroll
        for (int ks = 0; ks < 4; ++ks) {
            const int akidx = ks * 32 + lq * 8;
            const bf16x8 a = *(const bf16x8*)&xs[arow * 128 + (akidx ^ ((arow & 7) << 3))];
            #pragma unroll
            for (int n = 0; n < 8; ++n) {
                const int bn = n * 16 + lr;
                const bf16x8 b = *(const bf16x8*)(Wt + bn * 128 + akidx);  // global, L1
                acc[n] = __builtin_amdgcn_mfma_f32_16x16x32_bf16(a, b, acc[n], 0, 0, 0);
            }
        }

        // C/D layout: col = lr, row = lq*4 + j
        #pragma unroll
        for (int j = 0; j < 4; ++j) {
            const int row = rowBase + w * 16 + lq * 4 + j;
            if (row < kN) {
                unsigned short* orow = Xpb + (size_t)row * kF + lr;
                #pragma unroll
                for (int n = 0; n < 8; ++n) orow[n * 16] = f32_to_bf16(acc[n][j]);
            }
        }
    }
}

// ---------------------------------------------------------------------------
// Dispatch 3/4: row-parallel gather SpMM, 16 lanes/row (4 rows per wave64),
// 8-wide edge unroll (8 x 16B gathers in flight per group), f32 accumulate.
// Fused scale / relu; nontemporal record loads + output stores.
// ---------------------------------------------------------------------------
template <bool ROW_SCALE, bool RELU, bool OUT_BF16>
__global__ __launch_bounds__(256) void spmm_csr(const int* __restrict__ rs,
                                                const int* __restrict__ re,
                                                const unsigned long long* __restrict__ rec,
                                                const float* __restrict__ scale,
                                                const unsigned short* __restrict__ Xin,
                                                void* __restrict__ Xout) {
    const int tid = blockIdx.x * 256 + threadIdx.x;
    const int r = tid >> 4;          // grid = kN*16/256 exactly
    const int lane = tid & 15;

    const int s = rs[r];
    const int e = re[r];

    float acc[8];
    #pragma unroll
    for (int m = 0; m < 8; ++m) acc[m] = 0.f;

    for (int base = s; base < e; base += 16) {
        int cl = 0;
        float vl = 0.f;
        if (base + lane < e) {
            const unsigned long long p = __builtin_nontemporal_load(&rec[base + lane]);
            cl = (int)((unsigned int)p & 0x1FFFF);
            vl = __uint_as_float((unsigned int)(p >> 32));
        }
        const int m8 = (min(16, e - base) + 7) & ~7;
        for (int j = 0; j < m8; j += 8) {
            int cc[8];
            float ww[8];
            #pragma unroll
            for (int q = 0; q < 8; ++q) {
                cc[q] = __shfl(cl, j + q, 16);
                ww[q] = __shfl(vl, j + q, 16);
            }
            ushort8v xv[8];
            #pragma unroll
            for (int q = 0; q < 8; ++q)
                xv[q] = *(const ushort8v*)(Xin + (size_t)cc[q] * kF + lane * 8);
            #pragma unroll
            for (int q = 0; q < 8; ++q) {
                #pragma unroll
                for (int m = 0; m < 8; ++m)
                    acc[m] = fmaf(ww[q], bf16_to_f32(xv[q][m]), acc[m]);
            }
        }
    }
    if (ROW_SCALE) {
        const float k = scale[r];
        #pragma unroll
        for (int m = 0; m < 8; ++m) acc[m] *= k;
    }
    if (RELU) {
        #pragma unroll
        for (int m = 0; m < 8; ++m) acc[m] = fmaxf(acc[m], 0.f);
    }
    if (OUT_BF16) {
        ushort8v o;
        #pragma unroll
        for (int m = 0; m < 8; ++m) o[m] = f32_to_bf16(acc[m]);
        __builtin_nontemporal_store(
            o, (ushort8v*)((unsigned short*)Xout + (size_t)r * kF + lane * 8));
    } else {
        f32x4 o0, o1;
        o0.x = acc[0]; o0.y = acc[1]; o0.z = acc[2]; o0.w = acc[3];
        o1.x = acc[4]; o1.y = acc[5]; o1.z = acc[6]; o1.w = acc[7];
        f32x4* dst = (f32x4*)Xout + (size_t)r * 32 + lane * 2;
        __builtin_nontemporal_store(o0, dst);
        __builtin_nontemporal_store(o1, dst + 1);
    }
}

extern "C" void kernel_launch(void* const* d_in, const int* in_sizes, int n_in,
                              void* d_out, int out_size, void* d_ws, size_t ws_size,
                              hipStream_t stream) {
    const float* x    = (const float*)d_in[0];
    const float* W    = (const float*)d_in[1];
    const float* kern = (const float*)d_in[2];
    const int*   p0r  = (const int*)d_in[3];
    const int*   p0c  = (const int*)d_in[4];
    const float* p0v  = (const float*)d_in[5];
    const int*   p1r  = (const int*)d_in[6];
    const int*   p1c  = (const int*)d_in[7];
    const float* p1v  = (const float*)d_in[8];

    // raw record staging lives in d_out (25.7 MB of its 51.2 MB); dead after
    // sort_gemm, and dispatch 4 fully overwrites d_out with the output.
    unsigned long long* stg = (unsigned long long*)d_out;

    // ws layout (16B-aligned slabs), total ~82 MB
    char* w = (char*)d_ws;
    size_t off = 0;
    unsigned short* Xpb = (unsigned short*)(w + off); off += (size_t)kN * kF * 2; // 25.6 MB
    unsigned short* Xtb = (unsigned short*)(w + off); off += (size_t)kN * kF * 2; // 25.6 MB
    unsigned short* Wt = (unsigned short*)(w + off);  off += 128 * 128 * 2;       // 32 KB
    unsigned short* dir = (unsigned short*)(w + off);
    off += (size_t)2 * kChunkBlocks * kDirStride * 2;                             // 351 KB
    off = (off + 15) & ~(size_t)15;
    unsigned long long* sortedG = (unsigned long long*)(w + off);
    off += (size_t)2 * kBuckets * kBucketCap * 8;                                 // 28.8 MB
    int* rs = (int*)(w + off);                        off += (size_t)2 * kN * 4;  // 0.8 MB
    int* re = (int*)(w + off);                        off += (size_t)2 * kN * 4;  // 0.8 MB

    // 1) Wt = bf16(W^T)  ||  bucket both edge lists (coalesced, block-contig)
    scatter_transpose<<<kTransBlocks + 2 * kChunkBlocks, 256, 0, stream>>>(
        W, Wt, p0r, p0c, p0v, p1r, p1c, p1v, stg, dir);

    // 2) sort both matrices  ||  X'(bf16) = x @ W
    sort_gemm<<<kSortBlocks + kGemmBlocks, 512, 0, stream>>>(
        stg, dir, sortedG, rs, re, x, Wt, Xpb);

    // 3) Xt(bf16) = kernel * (phi0 @ X')
    spmm_csr<true, false, true><<<kRowBlocks16, 256, 0, stream>>>(
        rs, re, sortedG, kern, Xpb, Xtb);

    // 4) out(f32) = relu(phi1 @ Xt)
    spmm_csr<false, true, false><<<kRowBlocks16, 256, 0, stream>>>(
        rs + kN, re + kN, sortedG, nullptr, Xtb, (float*)d_out);
}

// Round 15
// 205.370 us; speedup vs baseline: 1.0298x; 1.0298x over previous
//
#include <hip/hip_runtime.h>

// Wavelet_Convolution: out = relu(phi1 @ (kernel * (phi0 @ (x @ W))))
// N=100000, F=128, NNZ=1.6M per sparse matrix (COO, int32 idx, f32 vals).
//
// Pipeline (4 dispatches, overlap-scheduled):
//   1) scatter_transpose: Wt = bf16(W^T) || coalesced bucket scatter (both)
//   2) sort_gemm:  sort matrix0 (391 blks) || X'(bf16) = x@W (782 blks)
//   3) sort_spmm:  sort matrix1 (391 blks, first) || spmm0: Xt = k*(phi0@X')
//      (6250 blks @512thr) — sort1 hides under spmm0
//   4) spmm_csr:   out(f32) = relu(phi1 @ Xt)

constexpr int kN = 100000;
constexpr int kF = 128;
constexpr int kNNZ = 1600000;

constexpr int kBuckets = (kN + 255) / 256;                  // 391 (256-row buckets)
constexpr int kBucketCap = 4608;                            // mean 4096 + 8 sigma
constexpr int kChunk = 7168;                                // edges per scatter block
constexpr int kChunkBlocks = (kNNZ + kChunk - 1) / kChunk;  // 224 per matrix
constexpr int kSlotsPerMat = kChunkBlocks * kChunk;         // 1,605,632
constexpr int kDirStride = kBuckets + 1;                    // 392 entries per chunk
constexpr int kTransBlocks = 64;
constexpr int kGemmBlocks = (kN + 127) / 128;               // 782 (128 rows, 512 thr)
constexpr int kSpmmBlocks512 = kN * 32 / 512;               // 6250 (16 rows/block)
constexpr int kRowBlocks = kN * 32 / 256;                   // 12500

typedef short bf16x8 __attribute__((ext_vector_type(8)));
typedef float f32x4 __attribute__((ext_vector_type(4)));
typedef unsigned short ushort4v __attribute__((ext_vector_type(4)));

__device__ __forceinline__ unsigned short f32_to_bf16(float f) {
    unsigned int u = __float_as_uint(f);
    u += 0x7fffu + ((u >> 16) & 1u);   // round-to-nearest-even
    return (unsigned short)(u >> 16);
}
__device__ __forceinline__ float bf16_to_f32(unsigned short h) {
    return __uint_as_float((unsigned int)h << 16);
}

// ---------------------------------------------------------------------------
// Dispatch 1: W transpose (blocks 0..63) + coalesced bucket scatter (rest).
// Record: hi32 = f32 val, lo32 = (localrow&255)<<17 | col (col < 2^17).
// ---------------------------------------------------------------------------
__global__ __launch_bounds__(256) void scatter_transpose(
    const float* __restrict__ W, unsigned short* __restrict__ Wt,
    const int* __restrict__ r0, const int* __restrict__ c0, const float* __restrict__ v0,
    const int* __restrict__ r1, const int* __restrict__ c1, const float* __restrict__ v1,
    unsigned long long* __restrict__ stg, unsigned short* __restrict__ dir) {
    const int t = threadIdx.x;
    if (blockIdx.x < kTransBlocks) {
        const int e = blockIdx.x * 256 + t;
        const int n = e & 127, k = e >> 7;
        Wt[n * 128 + k] = f32_to_bf16(W[e]);
        return;
    }

    __shared__ unsigned long long recs[kChunk];   // 56 KB
    __shared__ int hist[kDirStride];
    __shared__ int cur[kDirStride];
    __shared__ int sc2[256];

    const int b = blockIdx.x - kTransBlocks;      // 0..447
    const bool m1 = b >= kChunkBlocks;
    const int cb = m1 ? b - kChunkBlocks : b;
    const int* rows = m1 ? r1 : r0;
    const int* cols = m1 ? c1 : c0;
    const float* vals = m1 ? v1 : v0;
    unsigned long long* dst = stg + (size_t)b * kChunk;      // block-contiguous
    unsigned short* dirm = dir + (size_t)b * kDirStride;

    for (int i = t; i < kDirStride; i += 256) hist[i] = 0;
    __syncthreads();

    const int base0 = cb * kChunk;
    const int cnt = min(kNNZ - base0, kChunk);

    for (int j = t; j < cnt; j += 256) atomicAdd(&hist[rows[base0 + j] >> 8], 1);
    __syncthreads();

    // scan 392 bins (threads 0..195 own bins 2t, 2t+1)
    int s = 0;
    if (t < 196) s = hist[2 * t] + hist[2 * t + 1];
    sc2[t] = (t < 196) ? s : 0;
    __syncthreads();
    #pragma unroll
    for (int off = 1; off < 256; off <<= 1) {
        const int add = (t >= off) ? sc2[t - off] : 0;
        __syncthreads();
        sc2[t] += add;
        __syncthreads();
    }
    if (t < 196) {
        const int ex = sc2[t] - s;
        cur[2 * t] = ex;
        cur[2 * t + 1] = ex + hist[2 * t];
        dirm[2 * t] = (unsigned short)ex;
        dirm[2 * t + 1] = (unsigned short)(ex + hist[2 * t]);
    }
    __syncthreads();

    for (int j = t; j < cnt; j += 256) {
        const int idx = base0 + j;
        const int r = rows[idx];
        const int bk = r >> 8;
        const int pos = atomicAdd(&cur[bk], 1);
        const unsigned int key = ((unsigned int)(r & 255) << 17) | (unsigned int)cols[idx];
        recs[pos] = ((unsigned long long)__float_as_uint(vals[idx]) << 32) | key;
    }
    __syncthreads();

    for (int j = t; j < cnt; j += 256) dst[j] = recs[j];
}

// ---------------------------------------------------------------------------
// Shared device body: per-bucket counting sort (512 threads).
// matSel: 0 or 1 — which matrix's records/directory/outputs to use.
// ---------------------------------------------------------------------------
__device__ __forceinline__ void sort_bucket_body(
    char* smem, int bk, int matSel,
    const unsigned long long* __restrict__ stg,
    const unsigned short* __restrict__ dir,
    unsigned long long* __restrict__ sortedG,
    int* __restrict__ rs, int* __restrict__ re) {
    unsigned long long* sorted = (unsigned long long*)smem;       // 36864 B
    int* rlen = (int*)(smem + 36864);                             // 896 B
    int* gst  = (int*)(smem + 36864 + 896);                       // 896 B
    int* hist = (int*)(smem + 36864 + 1792);                      // 1024 B
    int* sc   = (int*)(smem + 36864 + 2816);                      // 1024 B
    int* cur  = (int*)(smem + 36864 + 3840);                      // 1024 B

    const int t = threadIdx.x;
    const unsigned long long* stgm = stg + (matSel ? (size_t)kSlotsPerMat : 0);

    if (t < kChunkBlocks) {
        const unsigned short* dd =
            dir + (size_t)(matSel * kChunkBlocks + t) * kDirStride;
        const int s = dd[bk];
        rlen[t] = dd[bk + 1] - s;
        gst[t] = t * kChunk + s;
    }
    if (t < 256) hist[t] = 0;
    __syncthreads();

    const int g = t >> 5;        // 16 groups of 32 lanes
    const int lane = t & 31;

    for (int blk = g; blk < kChunkBlocks; blk += 16) {
        const int len = rlen[blk];
        const int gs = gst[blk];
        for (int i = lane; i < len; i += 32) {
            const unsigned int lo = (unsigned int)stgm[gs + i];
            atomicAdd(&hist[(lo >> 17) & 255], 1);
        }
    }
    __syncthreads();

    const int v = (t < 256) ? hist[t] : 0;
    if (t < 256) sc[t] = v;
    __syncthreads();
    #pragma unroll
    for (int off = 1; off < 256; off <<= 1) {
        const int add = (t < 256 && t >= off) ? sc[t - off] : 0;
        __syncthreads();
        if (t < 256) sc[t] += add;
        __syncthreads();
    }
    if (t < 256) cur[t] = sc[t] - v;   // exclusive
    __syncthreads();

    for (int blk = g; blk < kChunkBlocks; blk += 16) {
        const int len = rlen[blk];
        const int gs = gst[blk];
        for (int i = lane; i < len; i += 32) {
            const unsigned long long p = stgm[gs + i];
            const int lrow = (int)(((unsigned int)p >> 17) & 255);
            sorted[atomicAdd(&cur[lrow], 1)] = p;
        }
    }
    __syncthreads();

    const int nrec = sc[255];
    const int bidx = matSel * kBuckets + bk;
    const size_t outBase = (size_t)bidx * kBucketCap;
    for (int j = t; j < nrec; j += 512) sortedG[outBase + j] = sorted[j];
    if (t < 256) {
        const int row = bk * 256 + t;
        if (row < kN) {
            const int rg = matSel * kN + row;
            rs[rg] = (int)outBase + sc[t] - hist[t];
            re[rg] = (int)outBase + sc[t];
        }
    }
}

// ---------------------------------------------------------------------------
// Shared device body: one output row of gather SpMM (32 lanes, 4-wide,
// r13-proven). Fused scale / relu; nontemporal record loads + output stores.
// ---------------------------------------------------------------------------
template <bool ROW_SCALE, bool RELU, bool OUT_BF16>
__device__ __forceinline__ void spmm_row_body(
    int r, int lane,
    const int* __restrict__ rs, const int* __restrict__ re,
    const unsigned long long* __restrict__ rec,
    const float* __restrict__ scale,
    const unsigned short* __restrict__ Xin,
    void* __restrict__ Xout) {
    const int s = rs[r];
    const int e = re[r];

    float4 acc = make_float4(0.f, 0.f, 0.f, 0.f);

    for (int base = s; base < e; base += 32) {
        int cl = 0;
        float vl = 0.f;
        if (base + lane < e) {
            const unsigned long long p = __builtin_nontemporal_load(&rec[base + lane]);
            cl = (int)((unsigned int)p & 0x1FFFF);
            vl = __uint_as_float((unsigned int)(p >> 32));
        }
        const int m4 = (min(32, e - base) + 3) & ~3;
        for (int j = 0; j < m4; j += 4) {
            const int c0 = __shfl(cl, j, 32);
            const int c1 = __shfl(cl, j + 1, 32);
            const int c2 = __shfl(cl, j + 2, 32);
            const int c3 = __shfl(cl, j + 3, 32);
            const float w0 = __shfl(vl, j, 32);
            const float w1 = __shfl(vl, j + 1, 32);
            const float w2 = __shfl(vl, j + 2, 32);
            const float w3 = __shfl(vl, j + 3, 32);
            const ushort4v x0 = *(const ushort4v*)(Xin + (size_t)c0 * kF + lane * 4);
            const ushort4v x1 = *(const ushort4v*)(Xin + (size_t)c1 * kF + lane * 4);
            const ushort4v x2 = *(const ushort4v*)(Xin + (size_t)c2 * kF + lane * 4);
            const ushort4v x3 = *(const ushort4v*)(Xin + (size_t)c3 * kF + lane * 4);
            acc.x = fmaf(w0, bf16_to_f32(x0.x), acc.x);
            acc.y = fmaf(w0, bf16_to_f32(x0.y), acc.y);
            acc.z = fmaf(w0, bf16_to_f32(x0.z), acc.z);
            acc.w = fmaf(w0, bf16_to_f32(x0.w), acc.w);
            acc.x = fmaf(w1, bf16_to_f32(x1.x), acc.x);
            acc.y = fmaf(w1, bf16_to_f32(x1.y), acc.y);
            acc.z = fmaf(w1, bf16_to_f32(x1.z), acc.z);
            acc.w = fmaf(w1, bf16_to_f32(x1.w), acc.w);
            acc.x = fmaf(w2, bf16_to_f32(x2.x), acc.x);
            acc.y = fmaf(w2, bf16_to_f32(x2.y), acc.y);
            acc.z = fmaf(w2, bf16_to_f32(x2.z), acc.z);
            acc.w = fmaf(w2, bf16_to_f32(x2.w), acc.w);
            acc.x = fmaf(w3, bf16_to_f32(x3.x), acc.x);
            acc.y = fmaf(w3, bf16_to_f32(x3.y), acc.y);
            acc.z = fmaf(w3, bf16_to_f32(x3.z), acc.z);
            acc.w = fmaf(w3, bf16_to_f32(x3.w), acc.w);
        }
    }
    if (ROW_SCALE) {
        const float k = scale[r];
        acc.x *= k; acc.y *= k; acc.z *= k; acc.w *= k;
    }
    if (RELU) {
        acc.x = fmaxf(acc.x, 0.f); acc.y = fmaxf(acc.y, 0.f);
        acc.z = fmaxf(acc.z, 0.f); acc.w = fmaxf(acc.w, 0.f);
    }
    if (OUT_BF16) {
        ushort4v o;
        o.x = f32_to_bf16(acc.x); o.y = f32_to_bf16(acc.y);
        o.z = f32_to_bf16(acc.z); o.w = f32_to_bf16(acc.w);
        __builtin_nontemporal_store(
            o, (ushort4v*)((unsigned short*)Xout + (size_t)r * kF + lane * 4));
    } else {
        f32x4 o;
        o.x = acc.x; o.y = acc.y; o.z = acc.z; o.w = acc.w;
        __builtin_nontemporal_store(o, (f32x4*)Xout + (size_t)r * 32 + lane);
    }
}

// ---------------------------------------------------------------------------
// Dispatch 2: sort matrix0 (blocks 0..390) || gemm (blocks 391..1172).
// ---------------------------------------------------------------------------
__global__ __launch_bounds__(512) void sort_gemm(
    const unsigned long long* __restrict__ stg,
    const unsigned short* __restrict__ dir,
    unsigned long long* __restrict__ sortedG,
    int* __restrict__ rs, int* __restrict__ re,
    const float* __restrict__ x, const unsigned short* __restrict__ Wt,
    unsigned short* __restrict__ Xpb) {
    __shared__ __align__(16) char smem[41728];
    const int t = threadIdx.x;

    if (blockIdx.x < kBuckets) {
        sort_bucket_body(smem, blockIdx.x, 0, stg, dir, sortedG, rs, re);
    } else {
        // ================= gemm branch (128 rows, 8 waves) =================
        unsigned short* xs = (unsigned short*)smem;     // 128x128 bf16 = 32 KB
        const int rowBase = (blockIdx.x - kBuckets) * 128;

        {
            const int lrow = t >> 2;                    // 0..127
            const int q = t & 3;
            int srow = rowBase + lrow;
            if (srow >= kN) srow = kN - 1;
            const float4* xr = (const float4*)(x + (size_t)srow * kF) + q * 8;
            #pragma unroll
            for (int i = 0; i < 8; ++i) {
                const float4 f = xr[i];
                ushort4v h;
                h.x = f32_to_bf16(f.x); h.y = f32_to_bf16(f.y);
                h.z = f32_to_bf16(f.z); h.w = f32_to_bf16(f.w);
                const int kidx = q * 32 + i * 4;
                *(ushort4v*)&xs[lrow * 128 + (kidx ^ ((lrow & 7) << 3))] = h;
            }
        }
        __syncthreads();

        const int w = t >> 6;        // wave 0..7 -> rows w*16..w*16+15
        const int l = t & 63;
        const int lr = l & 15;
        const int lq = l >> 4;

        f32x4 acc[8];
        #pragma unroll
        for (int n = 0; n < 8; ++n) acc[n] = (f32x4){0.f, 0.f, 0.f, 0.f};

        const int arow = w * 16 + lr;
        #pragma unroll
        for (int ks = 0; ks < 4; ++ks) {
            const int akidx = ks * 32 + lq * 8;
            const bf16x8 a = *(const bf16x8*)&xs[arow * 128 + (akidx ^ ((arow & 7) << 3))];
            #pragma unroll
            for (int n = 0; n < 8; ++n) {
                const int bn = n * 16 + lr;
                const bf16x8 b = *(const bf16x8*)(Wt + bn * 128 + akidx);  // global, L1
                acc[n] = __builtin_amdgcn_mfma_f32_16x16x32_bf16(a, b, acc[n], 0, 0, 0);
            }
        }

        // C/D layout: col = lr, row = lq*4 + j
        #pragma unroll
        for (int j = 0; j < 4; ++j) {
            const int row = rowBase + w * 16 + lq * 4 + j;
            if (row < kN) {
                unsigned short* orow = Xpb + (size_t)row * kF + lr;
                #pragma unroll
                for (int n = 0; n < 8; ++n) orow[n * 16] = f32_to_bf16(acc[n][j]);
            }
        }
    }
}

// ---------------------------------------------------------------------------
// Dispatch 3: sort matrix1 (blocks 0..390, co-resident first) ||
// spmm0 (blocks 391..6640, 512thr = 16 rows x 32 lanes): Xt = kern*(phi0@X').
// sort1 (~40us) hides under spmm0 (~60us).
// ---------------------------------------------------------------------------
__global__ __launch_bounds__(512) void sort_spmm(
    const unsigned long long* __restrict__ stg,
    const unsigned short* __restrict__ dir,
    unsigned long long* __restrict__ sortedG,
    int* __restrict__ rs, int* __restrict__ re,
    const float* __restrict__ kern,
    const unsigned short* __restrict__ Xpb,
    unsigned short* __restrict__ Xtb) {
    __shared__ __align__(16) char smem[41728];

    if (blockIdx.x < kBuckets) {
        sort_bucket_body(smem, blockIdx.x, 1, stg, dir, sortedG, rs, re);
    } else {
        const int t = threadIdx.x;
        const int r = (blockIdx.x - kBuckets) * 16 + (t >> 5);
        spmm_row_body<true, false, true>(r, t & 31, rs, re, sortedG, kern, Xpb, Xtb);
    }
}

// ---------------------------------------------------------------------------
// Dispatch 4: spmm1 — out(f32) = relu(phi1 @ Xt). r13-identical structure.
// ---------------------------------------------------------------------------
__global__ __launch_bounds__(256) void spmm_csr(const int* __restrict__ rs,
                                                const int* __restrict__ re,
                                                const unsigned long long* __restrict__ rec,
                                                const unsigned short* __restrict__ Xin,
                                                float* __restrict__ Xout) {
    const int tid = blockIdx.x * 256 + threadIdx.x;
    spmm_row_body<false, true, false>(tid >> 5, tid & 31, rs, re, rec, nullptr,
                                      Xin, Xout);
}

extern "C" void kernel_launch(void* const* d_in, const int* in_sizes, int n_in,
                              void* d_out, int out_size, void* d_ws, size_t ws_size,
                              hipStream_t stream) {
    const float* x    = (const float*)d_in[0];
    const float* W    = (const float*)d_in[1];
    const float* kern = (const float*)d_in[2];
    const int*   p0r  = (const int*)d_in[3];
    const int*   p0c  = (const int*)d_in[4];
    const float* p0v  = (const float*)d_in[5];
    const int*   p1r  = (const int*)d_in[6];
    const int*   p1c  = (const int*)d_in[7];
    const float* p1v  = (const float*)d_in[8];

    // raw record staging lives in d_out (25.7 MB of its 51.2 MB); still read
    // by sort1 in dispatch 3; dispatch 4 fully overwrites d_out with output.
    unsigned long long* stg = (unsigned long long*)d_out;

    // ws layout (16B-aligned slabs), total ~82 MB
    char* w = (char*)d_ws;
    size_t off = 0;
    unsigned short* Xpb = (unsigned short*)(w + off); off += (size_t)kN * kF * 2; // 25.6 MB
    unsigned short* Xtb = (unsigned short*)(w + off); off += (size_t)kN * kF * 2; // 25.6 MB
    unsigned short* Wt = (unsigned short*)(w + off);  off += 128 * 128 * 2;       // 32 KB
    unsigned short* dir = (unsigned short*)(w + off);
    off += (size_t)2 * kChunkBlocks * kDirStride * 2;                             // 351 KB
    off = (off + 15) & ~(size_t)15;
    unsigned long long* sortedG = (unsigned long long*)(w + off);
    off += (size_t)2 * kBuckets * kBucketCap * 8;                                 // 28.8 MB
    int* rs = (int*)(w + off);                        off += (size_t)2 * kN * 4;  // 0.8 MB
    int* re = (int*)(w + off);                        off += (size_t)2 * kN * 4;  // 0.8 MB

    // 1) Wt = bf16(W^T)  ||  bucket both edge lists (coalesced, block-contig)
    scatter_transpose<<<kTransBlocks + 2 * kChunkBlocks, 256, 0, stream>>>(
        W, Wt, p0r, p0c, p0v, p1r, p1c, p1v, stg, dir);

    // 2) sort matrix0  ||  X'(bf16) = x @ W
    sort_gemm<<<kBuckets + kGemmBlocks, 512, 0, stream>>>(
        stg, dir, sortedG, rs, re, x, Wt, Xpb);

    // 3) sort matrix1  ||  Xt(bf16) = kernel * (phi0 @ X')
    sort_spmm<<<kBuckets + kSpmmBlocks512, 512, 0, stream>>>(
        stg, dir, sortedG, rs, re, kern, Xpb, Xtb);

    // 4) out(f32) = relu(phi1 @ Xt)
    spmm_csr<<<kRowBlocks, 256, 0, stream>>>(rs + kN, re + kN, sortedG, Xtb,
                                             (float*)d_out);
}